// Round 1
// baseline (887.626 us; speedup 1.0000x reference)
//
#include <hip/hip_runtime.h>
#include <hip/hip_bf16.h>
#include <cstdint>

#define GLOBAL_AS __attribute__((address_space(1)))
#define LDS_AS    __attribute__((address_space(3)))

typedef __bf16 v8bf __attribute__((ext_vector_type(8)));
typedef __bf16 v4bf __attribute__((ext_vector_type(4)));
typedef float  v4f  __attribute__((ext_vector_type(4)));

// ---------------- f32 -> bf16 conversion ----------------
__global__ void cvt_f32_bf16(const float* __restrict__ in, __bf16* __restrict__ out, int n4) {
    int i = blockIdx.x * blockDim.x + threadIdx.x;
    if (i >= n4) return;
    float4 f = ((const float4*)in)[i];
    v4bf o;
    o[0] = (__bf16)f.x; o[1] = (__bf16)f.y; o[2] = (__bf16)f.z; o[3] = (__bf16)f.w;
    ((v4bf*)out)[i] = o;
}

// ---------------- GEMM: C[m][n] = sum_k A[m][k] * B[n][k] (+biases) ----------
// 128x128 tile, BK=32, 256 threads (4 waves, 2x2), each wave 4x4 of 16x16x32 MFMA.
// All dims assumed multiples of 128 (true for every call in this problem).
template <typename OutT>
__global__ void gemm_bt(const __bf16* __restrict__ A, int lda,
                        const __bf16* __restrict__ B, int ldb,
                        OutT* __restrict__ C, int ldc,
                        int K,
                        const float* __restrict__ bias_col,
                        const float* __restrict__ bias_row)
{
    __shared__ __align__(16) __bf16 As[128 * 32];
    __shared__ __align__(16) __bf16 Bs[128 * 32];
    const int tid  = threadIdx.x;
    const int wave = tid >> 6, lane = tid & 63;
    const int wr = wave >> 1, wc = wave & 1;
    const int quad = lane >> 4, l15 = lane & 15;
    const int bm = blockIdx.y, bn = blockIdx.x;

    const __bf16* Abase = A + (size_t)(bm * 128) * lda;
    const __bf16* Bbase = B + (size_t)(bn * 128) * ldb;

    v4f acc[4][4];
#pragma unroll
    for (int i = 0; i < 4; i++)
#pragma unroll
        for (int j = 0; j < 4; j++) acc[i][j] = (v4f){0.f, 0.f, 0.f, 0.f};

    const int ar = lane >> 2;        // row within a 16-row staging chunk
    const int ac = (lane & 3) * 8;   // col element offset (8 bf16 = 16B per lane)

    for (int kt = 0; kt < K; kt += 32) {
        __syncthreads();  // protect LDS from previous iteration's readers
#pragma unroll
        for (int i = 0; i < 2; i++) {
            const int r = wave * 32 + i * 16;  // wave-uniform 16-row chunk base
            __builtin_amdgcn_global_load_lds(
                (const GLOBAL_AS void*)(Abase + (size_t)(r + ar) * lda + kt + ac),
                (LDS_AS void*)(As + r * 32), 16, 0, 0);
            __builtin_amdgcn_global_load_lds(
                (const GLOBAL_AS void*)(Bbase + (size_t)(r + ar) * ldb + kt + ac),
                (LDS_AS void*)(Bs + r * 32), 16, 0, 0);
        }
        __syncthreads();  // drains vmcnt -> LDS tiles ready

        v8bf aF[4], bF[4];
#pragma unroll
        for (int i = 0; i < 4; i++)
            aF[i] = *(const v8bf*)(As + (wr * 64 + i * 16 + l15) * 32 + quad * 8);
#pragma unroll
        for (int j = 0; j < 4; j++)
            bF[j] = *(const v8bf*)(Bs + (wc * 64 + j * 16 + l15) * 32 + quad * 8);
#pragma unroll
        for (int i = 0; i < 4; i++)
#pragma unroll
            for (int j = 0; j < 4; j++)
                acc[i][j] = __builtin_amdgcn_mfma_f32_16x16x32_bf16(aF[i], bF[j], acc[i][j], 0, 0, 0);
    }

    // Epilogue: C/D layout = row: quad*4+r, col: lane&15 (m89/m91-verified)
#pragma unroll
    for (int i = 0; i < 4; i++) {
        const int row0 = bm * 128 + wr * 64 + i * 16 + quad * 4;
#pragma unroll
        for (int j = 0; j < 4; j++) {
            const int col = bn * 128 + wc * 64 + j * 16 + l15;
            const float bc = bias_col ? bias_col[col] : 0.f;
#pragma unroll
            for (int r = 0; r < 4; r++) {
                float v = acc[i][j][r] + bc;
                if (bias_row) v += bias_row[row0 + r];
                C[(size_t)(row0 + r) * ldc + col] = (OutT)v;
            }
        }
    }
}

// ---------------- row softmax: P = softmax(scale * S) , fp32 -> bf16 ----------
// One block (256 threads) per row of 4096.
__global__ void softmax_rows(const float* __restrict__ Sm, __bf16* __restrict__ P, float scale) {
    const int row = blockIdx.x;
    const int t = threadIdx.x;
    const int wave = t >> 6, lane = t & 63;
    const float4* src = (const float4*)(Sm + (size_t)row * 4096);
    float4 v[4];
    float m = -3.0e38f;
#pragma unroll
    for (int c = 0; c < 4; ++c) {
        v[c] = src[c * 256 + t];
        v[c].x *= scale; v[c].y *= scale; v[c].z *= scale; v[c].w *= scale;
        m = fmaxf(m, fmaxf(fmaxf(v[c].x, v[c].y), fmaxf(v[c].z, v[c].w)));
    }
#pragma unroll
    for (int o = 32; o > 0; o >>= 1) m = fmaxf(m, __shfl_xor(m, o, 64));
    __shared__ float red[8];
    if (lane == 0) red[wave] = m;
    __syncthreads();
    m = fmaxf(fmaxf(red[0], red[1]), fmaxf(red[2], red[3]));
    float s = 0.f;
#pragma unroll
    for (int c = 0; c < 4; ++c) {
        v[c].x = __expf(v[c].x - m); v[c].y = __expf(v[c].y - m);
        v[c].z = __expf(v[c].z - m); v[c].w = __expf(v[c].w - m);
        s += v[c].x + v[c].y + v[c].z + v[c].w;
    }
#pragma unroll
    for (int o = 32; o > 0; o >>= 1) s += __shfl_xor(s, o, 64);
    if (lane == 0) red[4 + wave] = s;
    __syncthreads();
    s = red[4] + red[5] + red[6] + red[7];
    const float inv = 1.f / s;
    v4bf* dst = (v4bf*)(P + (size_t)row * 4096);
#pragma unroll
    for (int c = 0; c < 4; ++c) {
        v4bf o;
        o[0] = (__bf16)(v[c].x * inv); o[1] = (__bf16)(v[c].y * inv);
        o[2] = (__bf16)(v[c].z * inv); o[3] = (__bf16)(v[c].w * inv);
        dst[c * 256 + t] = o;
    }
}

extern "C" void kernel_launch(void* const* d_in, const int* in_sizes, int n_in,
                              void* d_out, int out_size, void* d_ws, size_t ws_size,
                              hipStream_t stream)
{
    const float* x  = (const float*)d_in[0];   // [4,4096,1024]
    const float* Wq = (const float*)d_in[1];   // [1024,1024]
    const float* bq = (const float*)d_in[2];
    const float* Wk = (const float*)d_in[3];
    const float* bk = (const float*)d_in[4];
    const float* Wv = (const float*)d_in[5];
    const float* bv = (const float*)d_in[6];
    const float* Wo = (const float*)d_in[7];
    const float* bo = (const float*)d_in[8];
    float* out = (float*)d_out;

    constexpr int B = 4, S = 4096, D = 1024;
    constexpr size_t MS = (size_t)B * S;  // 16384 total rows

    char* w = (char*)d_ws;
    size_t used = 0;
    auto alloc = [&](size_t bytes) -> char* {
        char* p = w + used;
        used += (bytes + 255) & ~(size_t)255;
        return p;
    };
    __bf16* xb  = (__bf16*)alloc(MS * D * 2);        // 32 MiB (reused as ctx later)
    __bf16* wqb = (__bf16*)alloc((size_t)D * D * 2); // 2 MiB
    __bf16* wkb = (__bf16*)alloc((size_t)D * D * 2);
    __bf16* wvb = (__bf16*)alloc((size_t)D * D * 2);
    __bf16* wob = (__bf16*)alloc((size_t)D * D * 2);
    __bf16* qb  = (__bf16*)alloc(MS * D * 2);        // 32 MiB
    __bf16* kb  = (__bf16*)alloc(MS * D * 2);        // 32 MiB
    __bf16* vT  = (__bf16*)alloc((size_t)D * MS * 2);// 32 MiB, [1024][16384]
    float*  sc  = (float*)alloc((size_t)S * S * 4);  // 64 MiB, per-batch scores
    __bf16* pb  = (__bf16*)alloc((size_t)S * S * 2); // 32 MiB, per-batch probs
    __bf16* ctx = xb;  // xb is dead after the vT GEMM; stream order makes reuse safe
    if (used > ws_size) return;  // insufficient workspace -> visible failure

    auto cvt = [&](const float* src, __bf16* dst, size_t n) {
        int n4 = (int)(n / 4);
        cvt_f32_bf16<<<(n4 + 255) / 256, 256, 0, stream>>>(src, dst, n4);
    };
    cvt(x,  xb,  MS * D);
    cvt(Wq, wqb, (size_t)D * D);
    cvt(Wk, wkb, (size_t)D * D);
    cvt(Wv, wvb, (size_t)D * D);
    cvt(Wo, wob, (size_t)D * D);

    const dim3 blk(256);
    // q = x Wq^T + bq ; k = x Wk^T + bk    [16384 x 1024]
    gemm_bt<__bf16><<<dim3(D / 128, MS / 128), blk, 0, stream>>>(xb, D, wqb, D, qb, D, D, bq, nullptr);
    gemm_bt<__bf16><<<dim3(D / 128, MS / 128), blk, 0, stream>>>(xb, D, wkb, D, kb, D, D, bk, nullptr);
    // vT[a][m] = sum_d Wv[a][d] x[m][d] + bv[a]   [1024 x 16384]
    gemm_bt<__bf16><<<dim3(MS / 128, D / 128), blk, 0, stream>>>(wvb, D, xb, D, vT, (int)MS, D, nullptr, bv);

    const float scale = 0.03125f;  // 1/sqrt(1024)
    for (int b = 0; b < B; ++b) {
        const __bf16* qbb = qb + (size_t)b * S * D;
        const __bf16* kbb = kb + (size_t)b * S * D;
        // scores = q k^T  (fp32)   [4096 x 4096]
        gemm_bt<float><<<dim3(S / 128, S / 128), blk, 0, stream>>>(qbb, D, kbb, D, sc, S, D, nullptr, nullptr);
        // P = softmax(scale * scores)  -> bf16
        softmax_rows<<<S, 256, 0, stream>>>(sc, pb, scale);
        // ctx = P v   (via vT as B^T)   [4096 x 1024]
        gemm_bt<__bf16><<<dim3(D / 128, S / 128), blk, 0, stream>>>(
            pb, S, vT + (size_t)b * S, (int)MS, ctx + (size_t)b * S * D, D, S, nullptr, nullptr);
    }
    // out = ctx Wo^T + bo  (fp32 -> d_out)
    gemm_bt<float><<<dim3(D / 128, MS / 128), blk, 0, stream>>>(ctx, D, wob, D, out, D, D, bo, nullptr);
}